// Round 1
// baseline (510.319 us; speedup 1.0000x reference)
//
#include <hip/hip_runtime.h>

typedef short bf16x8 __attribute__((ext_vector_type(8)));
typedef short bf16x4 __attribute__((ext_vector_type(4)));
typedef float f32x4 __attribute__((ext_vector_type(4)));

#define MFMA16x16x32(a, b, c) __builtin_amdgcn_mfma_f32_16x16x32_bf16(a, b, c, 0, 0, 0)

__device__ __forceinline__ short f2bf(float f) {
  union { float f; unsigned u; } x; x.f = f;
  unsigned r = x.u + 0x7FFFu + ((x.u >> 16) & 1u);
  return (short)(r >> 16);
}

// XOR-swizzle for 128B rows: 16B chunk index XORed with (row&7).
__device__ __forceinline__ int swz(int row, int bytecol) {
  return row * 128 + (((bytecol >> 4) ^ (row & 7)) << 4) + (bytecol & 15);
}

__global__ void cvt_w(const float* __restrict__ src, short* __restrict__ dst, int n4) {
  int i = blockIdx.x * 256 + threadIdx.x;
  if (i >= n4) return;
  float4 v = reinterpret_cast<const float4*>(src)[i];
  bf16x4 o;
  o[0] = f2bf(v.x); o[1] = f2bf(v.y); o[2] = f2bf(v.z); o[3] = f2bf(v.w);
  reinterpret_cast<bf16x4*>(dst)[i] = o;
}

// C = A @ B^T.  A: [M x K] (f32 or bf16), B: [N x K] bf16 row-major (K contiguous).
// OUT_F32: C = f32 with bias; else C = bf16.
template<bool A_F32, bool OUT_F32>
__global__ __launch_bounds__(256, 2) void gemm_bt(
    const void* __restrict__ Ap, const short* __restrict__ Bp,
    void* __restrict__ Cp, const float* __restrict__ bias,
    int M, int N, int K)
{
  constexpr int BM = 128, BN = 128, BK = 64;
  __shared__ short As[BM * BK];
  __shared__ short Bs[BN * BK];
  const int tid = threadIdx.x;
  const int l = tid & 63, w = tid >> 6;
  const int nb = N / BN;
  const int bm = (blockIdx.x / nb) * BM;
  const int bn = (blockIdx.x % nb) * BN;
  const int wm = (w >> 1) * 64, wn = (w & 1) * 64;

  f32x4 acc[4][4] = {};

  const int nkt = K / BK;
  for (int kt = 0; kt < nkt; ++kt) {
    const int k0 = kt * BK;
    if (A_F32) {
      const float* A = (const float*)Ap;
      #pragma unroll
      for (int i = 0; i < 8; ++i) {
        int f = tid + i * 256;                  // float4 index within 128x64 tile
        int row = f >> 4, c4 = f & 15;
        float4 v = *(const float4*)(A + (size_t)(bm + row) * K + k0 + c4 * 4);
        bf16x4 o;
        o[0] = f2bf(v.x); o[1] = f2bf(v.y); o[2] = f2bf(v.z); o[3] = f2bf(v.w);
        *(bf16x4*)((char*)As + swz(row, c4 * 8)) = o;
      }
    } else {
      const short* A = (const short*)Ap;
      #pragma unroll
      for (int i = 0; i < 4; ++i) {
        int idx = tid + i * 256;                // 16B chunk index
        int row = idx >> 3, c = idx & 7;
        bf16x8 v = *(const bf16x8*)(A + (size_t)(bm + row) * K + k0 + c * 8);
        *(bf16x8*)((char*)As + swz(row, c * 16)) = v;
      }
    }
    #pragma unroll
    for (int i = 0; i < 4; ++i) {
      int idx = tid + i * 256;
      int row = idx >> 3, c = idx & 7;
      bf16x8 v = *(const bf16x8*)(Bp + (size_t)(bn + row) * K + k0 + c * 8);
      *(bf16x8*)((char*)Bs + swz(row, c * 16)) = v;
    }
    __syncthreads();
    #pragma unroll
    for (int kk = 0; kk < 2; ++kk) {
      const int ab = kk * 64 + (l >> 4) * 16;   // byte col of this lane's 16B frag
      bf16x8 a[4], b[4];
      #pragma unroll
      for (int i = 0; i < 4; ++i) {
        a[i] = *(const bf16x8*)((const char*)As + swz(wm + i * 16 + (l & 15), ab));
        b[i] = *(const bf16x8*)((const char*)Bs + swz(wn + i * 16 + (l & 15), ab));
      }
      #pragma unroll
      for (int mf = 0; mf < 4; ++mf)
        #pragma unroll
        for (int nf = 0; nf < 4; ++nf)
          acc[mf][nf] = MFMA16x16x32(a[mf], b[nf], acc[mf][nf]);
    }
    __syncthreads();
  }

  #pragma unroll
  for (int mf = 0; mf < 4; ++mf) {
    #pragma unroll
    for (int nf = 0; nf < 4; ++nf) {
      const int col = bn + wn + nf * 16 + (l & 15);
      float bv = 0.f;
      if (OUT_F32) bv = bias[col];
      #pragma unroll
      for (int r = 0; r < 4; ++r) {
        const int row = bm + wm + mf * 16 + (l >> 4) * 4 + r;
        if (OUT_F32)
          ((float*)Cp)[(size_t)row * N + col] = acc[mf][nf][r] + bv;
        else
          ((short*)Cp)[(size_t)row * N + col] = f2bf(acc[mf][nf][r]);
      }
    }
  }
}

// Flash attention: one block = 4 waves = 128 q rows of one (n,h); KVB=64.
__global__ __launch_bounds__(256, 2) void attn_fwd(
    const short* __restrict__ Q, const short* __restrict__ K,
    const short* __restrict__ V, const int* __restrict__ mask,
    short* __restrict__ O)
{
  constexpr int S = 2048, E = 1024, QB = 128, KB = 64;
  __shared__ short Vt[64 * 64];       // [d][kv] swizzled, rows 128B
  __shared__ short Pl[4 * 32 * 64];   // per-wave 32x64 P, swizzled
  const int tid = threadIdx.x, l = tid & 63, w = tid >> 6;
  const int nQB = S / QB;             // 16
  const int nh = blockIdx.x / nQB, qt = blockIdx.x % nQB;
  const int n = nh >> 4, h = nh & 15;
  const size_t base = (size_t)n * S * E + (size_t)h * 64;
  const short* Qb = Q + base;
  const short* Kb = K + base;
  const short* Vb = V + base;
  short* Ob = O + base;
  const int* mb = mask + n * S;

  // Q fragments (held in registers for the whole block)
  bf16x8 qf[2][2];
  #pragma unroll
  for (int mf = 0; mf < 2; ++mf)
    #pragma unroll
    for (int kk = 0; kk < 2; ++kk) {
      int row = qt * QB + w * 32 + mf * 16 + (l & 15);
      qf[mf][kk] = *(const bf16x8*)(Qb + (size_t)row * E + kk * 32 + (l >> 4) * 8);
    }

  f32x4 o[2][4] = {};
  float m_r[2][4], l_r[2][4];
  #pragma unroll
  for (int mf = 0; mf < 2; ++mf)
    #pragma unroll
    for (int r = 0; r < 4; ++r) { m_r[mf][r] = -1e30f; l_r[mf][r] = 0.f; }

  char* Pw = (char*)Pl + w * 4096;

  for (int kv0 = 0; kv0 < S; kv0 += KB) {
    // ---- QK^T (K frags straight from global; L2-resident) ----
    f32x4 s[2][4] = {};
    #pragma unroll
    for (int kk = 0; kk < 2; ++kk)
      #pragma unroll
      for (int nf = 0; nf < 4; ++nf) {
        int kr = kv0 + nf * 16 + (l & 15);
        bf16x8 kb = *(const bf16x8*)(Kb + (size_t)kr * E + kk * 32 + (l >> 4) * 8);
        #pragma unroll
        for (int mf = 0; mf < 2; ++mf)
          s[mf][nf] = MFMA16x16x32(qf[mf][kk], kb, s[mf][nf]);
      }
    // scale + mask
    #pragma unroll
    for (int nf = 0; nf < 4; ++nf) {
      bool mz = (mb[kv0 + nf * 16 + (l & 15)] == 0);
      #pragma unroll
      for (int mf = 0; mf < 2; ++mf) {
        s[mf][nf] = s[mf][nf] * 0.125f;
        if (mz) {
          #pragma unroll
          for (int r = 0; r < 4; ++r) s[mf][nf][r] = -1e20f;
        }
      }
    }
    __syncthreads();   // previous tile's PV reads of Vt/P are done
    // ---- online softmax (rows live across 16-lane groups) ----
    #pragma unroll
    for (int mf = 0; mf < 2; ++mf)
      #pragma unroll
      for (int r = 0; r < 4; ++r) {
        float mx = fmaxf(fmaxf(s[mf][0][r], s[mf][1][r]),
                         fmaxf(s[mf][2][r], s[mf][3][r]));
        #pragma unroll
        for (int d = 1; d < 16; d <<= 1) mx = fmaxf(mx, __shfl_xor(mx, d, 64));
        float mo = m_r[mf][r];
        float mn = fmaxf(mo, mx);
        float al = __expf(mo - mn);
        float rs = 0.f;
        #pragma unroll
        for (int nf = 0; nf < 4; ++nf) {
          float p = __expf(s[mf][nf][r] - mn);
          s[mf][nf][r] = p;
          rs += p;
        }
        #pragma unroll
        for (int d = 1; d < 16; d <<= 1) rs += __shfl_xor(rs, d, 64);
        l_r[mf][r] = l_r[mf][r] * al + rs;
        m_r[mf][r] = mn;
        #pragma unroll
        for (int nf = 0; nf < 4; ++nf) o[mf][nf][r] *= al;
      }
    // ---- write P (bf16) to per-wave LDS in A-fragment-readable layout ----
    #pragma unroll
    for (int mf = 0; mf < 2; ++mf)
      #pragma unroll
      for (int nf = 0; nf < 4; ++nf)
        #pragma unroll
        for (int r = 0; r < 4; ++r) {
          int row = mf * 16 + (l >> 4) * 4 + r;
          int col = nf * 16 + (l & 15);
          *(short*)(Pw + swz(row, col * 2)) = f2bf(s[mf][nf][r]);
        }
    // ---- stage V^T cooperatively ----
    {
      int kvr = tid >> 2;
      int d0 = (tid & 3) * 16;
      const short* vp = Vb + (size_t)(kv0 + kvr) * E + d0;
      bf16x8 v0 = *(const bf16x8*)(vp);
      bf16x8 v1 = *(const bf16x8*)(vp + 8);
      #pragma unroll
      for (int j = 0; j < 8; ++j) {
        *(short*)((char*)Vt + swz(d0 + j, kvr * 2)) = v0[j];
        *(short*)((char*)Vt + swz(d0 + 8 + j, kvr * 2)) = v1[j];
      }
    }
    __syncthreads();
    // ---- PV ----
    #pragma unroll
    for (int kk = 0; kk < 2; ++kk) {
      const int ab = kk * 64 + (l >> 4) * 16;
      bf16x8 pa[2], vb[4];
      #pragma unroll
      for (int mf = 0; mf < 2; ++mf)
        pa[mf] = *(const bf16x8*)(Pw + swz(mf * 16 + (l & 15), ab));
      #pragma unroll
      for (int nf = 0; nf < 4; ++nf)
        vb[nf] = *(const bf16x8*)((char*)Vt + swz(nf * 16 + (l & 15), ab));
      #pragma unroll
      for (int mf = 0; mf < 2; ++mf)
        #pragma unroll
        for (int nf = 0; nf < 4; ++nf)
          o[mf][nf] = MFMA16x16x32(pa[mf], vb[nf], o[mf][nf]);
    }
  }
  // ---- epilogue: normalize and store (overwrites this block's own Q rows) ----
  #pragma unroll
  for (int mf = 0; mf < 2; ++mf)
    #pragma unroll
    for (int r = 0; r < 4; ++r) {
      float inv = 1.f / l_r[mf][r];
      int row = qt * QB + w * 32 + mf * 16 + (l >> 4) * 4 + r;
      #pragma unroll
      for (int nf = 0; nf < 4; ++nf) {
        int col = nf * 16 + (l & 15);
        Ob[(size_t)row * E + col] = f2bf(o[mf][nf][r] * inv);
      }
    }
}

extern "C" void kernel_launch(void* const* d_in, const int* in_sizes, int n_in,
                              void* d_out, int out_size, void* d_ws, size_t ws_size,
                              hipStream_t stream) {
  (void)in_sizes; (void)n_in; (void)out_size; (void)ws_size;
  const float* values = (const float*)d_in[0];
  const float* keys   = (const float*)d_in[1];
  const float* query  = (const float*)d_in[2];
  const int*   mask   = (const int*)d_in[3];
  const float* Wv = (const float*)d_in[4];
  const float* Wk = (const float*)d_in[5];
  const float* Wq = (const float*)d_in[6];
  const float* Wo = (const float*)d_in[7];
  const float* bo = (const float*)d_in[8];
  float* out = (float*)d_out;

  constexpr int N = 4, S = 2048, E = 1024;
  constexpr int M = N * S;  // 8192

  // workspace layout (bf16): Q, K, V, then 4 weight matrices.  ~58.7 MB.
  short* Qb  = (short*)d_ws;
  short* Kb  = Qb  + (size_t)M * E;
  short* Vb  = Kb  + (size_t)M * E;
  short* Wqb = Vb  + (size_t)M * E;
  short* Wkb = Wqb + (size_t)E * E;
  short* Wvb = Wkb + (size_t)E * E;
  short* Wob = Wvb + (size_t)E * E;

  const int n4 = E * E / 4;
  cvt_w<<<n4 / 256, 256, 0, stream>>>(Wq, Wqb, n4);
  cvt_w<<<n4 / 256, 256, 0, stream>>>(Wk, Wkb, n4);
  cvt_w<<<n4 / 256, 256, 0, stream>>>(Wv, Wvb, n4);
  cvt_w<<<n4 / 256, 256, 0, stream>>>(Wo, Wob, n4);

  dim3 gg((M / 128) * (E / 128));  // 512 blocks
  gemm_bt<true, false><<<gg, 256, 0, stream>>>(query,  Wqb, Qb, nullptr, M, E, E);
  gemm_bt<true, false><<<gg, 256, 0, stream>>>(keys,   Wkb, Kb, nullptr, M, E, E);
  gemm_bt<true, false><<<gg, 256, 0, stream>>>(values, Wvb, Vb, nullptr, M, E, E);

  // attention output aliases Qb (each block consumes its Q rows into registers first)
  attn_fwd<<<64 * (S / 128), 256, 0, stream>>>(Qb, Kb, Vb, mask, Qb);

  gemm_bt<false, true><<<gg, 256, 0, stream>>>(Qb, Wob, out, bo, M, E, E);
}

// Round 3
// 415.863 us; speedup vs baseline: 1.2271x; 1.2271x over previous
//
#include <hip/hip_runtime.h>

typedef short bf16x8 __attribute__((ext_vector_type(8)));
typedef short bf16x4 __attribute__((ext_vector_type(4)));
typedef float f32x4 __attribute__((ext_vector_type(4)));
typedef float f32x16 __attribute__((ext_vector_type(16)));

#define MFMA16x16x32(a, b, c) __builtin_amdgcn_mfma_f32_16x16x32_bf16(a, b, c, 0, 0, 0)
#define MFMA32(a, b, c) __builtin_amdgcn_mfma_f32_32x32x16_bf16(a, b, c, 0, 0, 0)

__device__ __forceinline__ short f2bf(float f) {
  union { float f; unsigned u; } x; x.f = f;
  unsigned r = x.u + 0x7FFFu + ((x.u >> 16) & 1u);
  return (short)(r >> 16);
}

// pack two f32 -> 2xbf16 word (src0 in low half)
__device__ __forceinline__ unsigned pkbf(float a, float b) {
  unsigned r; asm("v_cvt_pk_bf16_f32 %0, %1, %2" : "=v"(r) : "v"(a), "v"(b)); return r;
}

// XOR-swizzle for 128B rows: 16B chunk index XORed with (row&7).
__device__ __forceinline__ int swz(int row, int bytecol) {
  return row * 128 + (((bytecol >> 4) ^ (row & 7)) << 4) + (bytecol & 15);
}

__global__ void cvt_w(const float* __restrict__ src, short* __restrict__ dst, int n4) {
  int i = blockIdx.x * 256 + threadIdx.x;
  if (i >= n4) return;
  float4 v = reinterpret_cast<const float4*>(src)[i];
  bf16x4 o;
  o[0] = f2bf(v.x); o[1] = f2bf(v.y); o[2] = f2bf(v.z); o[3] = f2bf(v.w);
  reinterpret_cast<bf16x4*>(dst)[i] = o;
}

// mask[N*S] ints -> bitmask words (32 k's per word)
__global__ void mask_bits(const int* __restrict__ mask, unsigned* __restrict__ mb) {
  int t = blockIdx.x * 64 + threadIdx.x;   // 256 words total
  unsigned b = 0;
  const int* p = mask + t * 32;
  for (int j = 0; j < 32; ++j) b |= (p[j] != 0 ? 1u : 0u) << j;
  mb[t] = b;
}

// C = A @ B^T.  A: [M x K] (f32 or bf16), B: [N x K] bf16 row-major.
// OMODE 0: bf16 out, scaled by oscale.  OMODE 1: f32 out + bias.
template<bool A_F32, int OMODE>
__global__ __launch_bounds__(256, 2) void gemm_bt(
    const void* __restrict__ Ap, const short* __restrict__ Bp,
    void* __restrict__ Cp, const float* __restrict__ bias,
    int M, int N, int K, float oscale)
{
  constexpr int BM = 128, BN = 128, BK = 64;
  __shared__ short As[BM * BK];
  __shared__ short Bs[BN * BK];
  const int tid = threadIdx.x;
  const int l = tid & 63, w = tid >> 6;
  const int nb = N / BN;
  const int bm = (blockIdx.x / nb) * BM;
  const int bn = (blockIdx.x % nb) * BN;
  const int wm = (w >> 1) * 64, wn = (w & 1) * 64;

  f32x4 acc[4][4] = {};

  const int nkt = K / BK;
  for (int kt = 0; kt < nkt; ++kt) {
    const int k0 = kt * BK;
    if (A_F32) {
      const float* A = (const float*)Ap;
      #pragma unroll
      for (int i = 0; i < 8; ++i) {
        int f = tid + i * 256;
        int row = f >> 4, c4 = f & 15;
        float4 v = *(const float4*)(A + (size_t)(bm + row) * K + k0 + c4 * 4);
        bf16x4 o;
        o[0] = f2bf(v.x); o[1] = f2bf(v.y); o[2] = f2bf(v.z); o[3] = f2bf(v.w);
        *(bf16x4*)((char*)As + swz(row, c4 * 8)) = o;
      }
    } else {
      const short* A = (const short*)Ap;
      #pragma unroll
      for (int i = 0; i < 4; ++i) {
        int idx = tid + i * 256;
        int row = idx >> 3, c = idx & 7;
        bf16x8 v = *(const bf16x8*)(A + (size_t)(bm + row) * K + k0 + c * 8);
        *(bf16x8*)((char*)As + swz(row, c * 16)) = v;
      }
    }
    #pragma unroll
    for (int i = 0; i < 4; ++i) {
      int idx = tid + i * 256;
      int row = idx >> 3, c = idx & 7;
      bf16x8 v = *(const bf16x8*)(Bp + (size_t)(bn + row) * K + k0 + c * 8);
      *(bf16x8*)((char*)Bs + swz(row, c * 16)) = v;
    }
    __syncthreads();
    #pragma unroll
    for (int kk = 0; kk < 2; ++kk) {
      const int ab = kk * 64 + (l >> 4) * 16;
      bf16x8 a[4], b[4];
      #pragma unroll
      for (int i = 0; i < 4; ++i) {
        a[i] = *(const bf16x8*)((const char*)As + swz(wm + i * 16 + (l & 15), ab));
        b[i] = *(const bf16x8*)((const char*)Bs + swz(wn + i * 16 + (l & 15), ab));
      }
      #pragma unroll
      for (int mf = 0; mf < 4; ++mf)
        #pragma unroll
        for (int nf = 0; nf < 4; ++nf)
          acc[mf][nf] = MFMA16x16x32(a[mf], b[nf], acc[mf][nf]);
    }
    __syncthreads();
  }

  #pragma unroll
  for (int mf = 0; mf < 4; ++mf) {
    #pragma unroll
    for (int nf = 0; nf < 4; ++nf) {
      const int col = bn + wn + nf * 16 + (l & 15);
      float bv = 0.f;
      if (OMODE == 1) bv = bias[col];
      #pragma unroll
      for (int r = 0; r < 4; ++r) {
        const int row = bm + wm + mf * 16 + (l >> 4) * 4 + r;
        if (OMODE == 1)
          ((float*)Cp)[(size_t)row * N + col] = acc[mf][nf][r] + bv;
        else
          ((short*)Cp)[(size_t)row * N + col] = f2bf(acc[mf][nf][r] * oscale);
      }
    }
  }
}

// Vb [N*S][E] bf16 -> Vt [(n*16+h)*64 + d][S] bf16   (per-head transpose)
__global__ __launch_bounds__(256) void vtrans(const short* __restrict__ Vb,
                                              short* __restrict__ Vt) {
  __shared__ short T[64 * 72];   // [d][s], rows padded to 144B
  const int bid = blockIdx.x;
  const int st = bid & 31, h = (bid >> 5) & 15, n = bid >> 9;
  const int s0 = st * 64;
  const int t = threadIdx.x;
  {
    int s = t >> 2, c = t & 3;
    const short* src = Vb + (size_t)(n * 2048 + s0 + s) * 1024 + h * 64;
    #pragma unroll
    for (int half = 0; half < 2; ++half) {
      int d0 = (c + half * 4) * 8;
      bf16x8 v = *(const bf16x8*)(src + d0);
      #pragma unroll
      for (int j = 0; j < 8; ++j) T[(d0 + j) * 72 + s] = v[j];
    }
  }
  __syncthreads();
  {
    int d = t >> 2, sc = t & 3;
    short* dst = Vt + ((size_t)(n * 16 + h) * 64 + d) * 2048 + s0;
    #pragma unroll
    for (int j = 0; j < 2; ++j) {
      int chunk = sc * 2 + j;
      bf16x8 v = *(const bf16x8*)(&T[d * 72 + chunk * 8]);
      *(bf16x8*)(dst + chunk * 8) = v;
    }
  }
}

// Swapped-operand flash attention: 1 wave per block, 32 q-rows per wave.
// S^T = mfma(K, Q): lane owns q = l&31; k rows (16 regs) per 32-half.
// Softmax in-register; cross-half exchanges via __shfl_xor(.,32) only.
// O^T = mfma(Vt, P^T); l_r summed from the bf16-rounded P words (exact
// numerator/denominator consistency).
__global__ __launch_bounds__(64, 4) void attn32(
    const short* __restrict__ Q, const short* __restrict__ K,
    const short* __restrict__ Vt, const unsigned* __restrict__ mbits,
    short* __restrict__ O)
{
  constexpr int S = 2048, E = 1024;
  __shared__ short OL[32 * 72];
  const int l = threadIdx.x & 63;
  const int bid = blockIdx.x;
  const int nh = (bid & 7) * 8 + ((bid >> 3) & 7);   // same-nh blocks -> same XCD
  const int qt = bid >> 6;                            // 0..63
  const int n = nh >> 4, h = nh & 15;
  const int lq = l & 31, hl = l >> 5, hl8 = hl * 8;

  const short* Qp = Q + (size_t)(n * S + qt * 32 + lq) * E + h * 64 + hl8;
  const short* Kp = K + (size_t)(n * S + lq) * E + h * 64 + hl8;
  const short* Vp = Vt + ((size_t)(n * 16 + h) * 64 + lq) * S + hl8;
  const unsigned* mbp = mbits + n * (S / 32);

  bf16x8 qf[4];
  #pragma unroll
  for (int dc = 0; dc < 4; ++dc) qf[dc] = *(const bf16x8*)(Qp + dc * 16);

  f32x16 o0 = {}, o1 = {};
  float m_r = -3.0e38f, l_r = 0.f;

  for (int kv0 = 0; kv0 < S; kv0 += 64) {
    // ---- S^T = K . Q^T over d=64 (4 chunks of 16) ----
    f32x16 s0 = {}, s1 = {};
    #pragma unroll
    for (int dc = 0; dc < 4; ++dc) {
      bf16x8 k0 = *(const bf16x8*)(Kp + (size_t)kv0 * E + dc * 16);
      bf16x8 k1 = *(const bf16x8*)(Kp + (size_t)(kv0 + 32) * E + dc * 16);
      s0 = MFMA32(k0, qf[dc], s0);
      s1 = MFMA32(k1, qf[dc], s1);
    }
    // ---- mask (wave-uniform fast path: all ones) ----
    unsigned mw0 = mbp[kv0 >> 5], mw1 = mbp[(kv0 >> 5) + 1];
    if ((mw0 & mw1) != 0xffffffffu) {
      #pragma unroll
      for (int r = 0; r < 16; ++r) {
        int kl = (r & 3) + 8 * (r >> 2) + 4 * hl;
        if (!((mw0 >> kl) & 1)) s0[r] = -1e30f;
        if (!((mw1 >> kl) & 1)) s1[r] = -1e30f;
      }
    }
    // ---- row max: 31 in-lane fmax + 1 shfl_xor(32) ----
    float pm = s0[0];
    #pragma unroll
    for (int r = 1; r < 16; ++r) pm = fmaxf(pm, s0[r]);
    #pragma unroll
    for (int r = 0; r < 16; ++r) pm = fmaxf(pm, s1[r]);
    pm = fmaxf(pm, __shfl_xor(pm, 32));
    // ---- online rescale (exact skip when no new max) ----
    if (!__all(pm <= m_r)) {
      float mn = fmaxf(m_r, pm);
      float al = exp2f(m_r - mn);
      m_r = mn; l_r *= al;
      #pragma unroll
      for (int r = 0; r < 16; ++r) { o0[r] *= al; o1[r] *= al; }
    }
    // ---- p = exp2(s - m) (log2-domain logits) ----
    #pragma unroll
    for (int r = 0; r < 16; ++r) s0[r] = exp2f(s0[r] - m_r);
    #pragma unroll
    for (int r = 0; r < 16; ++r) s1[r] = exp2f(s1[r] - m_r);
    // ---- build P^T frags (cvt_pk + shfl_xor), accumulate O^T, sum l ----
    float rs = 0.f;
    #pragma unroll
    for (int cc = 0; cc < 4; ++cc) {
      const f32x16& sv = (cc < 2) ? s0 : s1;
      const int ob = (cc & 1) * 8;
      unsigned x0 = pkbf(sv[ob + 0], sv[ob + 1]);
      unsigned x1 = pkbf(sv[ob + 2], sv[ob + 3]);
      unsigned y0 = pkbf(sv[ob + 4], sv[ob + 5]);
      unsigned y1 = pkbf(sv[ob + 6], sv[ob + 7]);
      // send what the partner half needs, receive what we need
      unsigned r0 = (unsigned)__shfl_xor((int)(hl ? x0 : y0), 32);
      unsigned r1 = (unsigned)__shfl_xor((int)(hl ? x1 : y1), 32);
      union { unsigned u[4]; bf16x8 v; } pf;
      pf.u[0] = hl ? r0 : x0;
      pf.u[1] = hl ? r1 : x1;
      pf.u[2] = hl ? y0 : r0;
      pf.u[3] = hl ? y1 : r1;
      #pragma unroll
      for (int wi = 0; wi < 4; ++wi) {
        rs += __uint_as_float(pf.u[wi] << 16);
        rs += __uint_as_float(pf.u[wi] & 0xffff0000u);
      }
      bf16x8 v0 = *(const bf16x8*)(Vp + kv0 + cc * 16);
      bf16x8 v1 = *(const bf16x8*)(Vp + (size_t)32 * S + kv0 + cc * 16);
      o0 = MFMA32(v0, pf.v, o0);
      o1 = MFMA32(v1, pf.v, o1);
    }
    rs += __shfl_xor(rs, 32);
    l_r += rs;
  }
  // ---- epilogue: normalize (RNE), transpose via LDS, coalesced store ----
  const float inv = 1.f / l_r;
  #pragma unroll
  for (int g = 0; g < 4; ++g) {
    bf16x4 t0, t1;
    #pragma unroll
    for (int i = 0; i < 4; ++i) {
      t0[i] = f2bf(o0[g * 4 + i] * inv);
      t1[i] = f2bf(o1[g * 4 + i] * inv);
    }
    *(bf16x4*)(OL + lq * 72 + g * 8 + hl * 4) = t0;
    *(bf16x4*)(OL + lq * 72 + 32 + g * 8 + hl * 4) = t1;
  }
  {
    int q = l >> 1, half = l & 1;
    short* dst = O + (size_t)(n * S + qt * 32 + q) * E + h * 64 + half * 32;
    const short* src = OL + q * 72 + half * 32;
    #pragma unroll
    for (int c = 0; c < 4; ++c)
      *(bf16x8*)(dst + c * 8) = *(const bf16x8*)(src + c * 8);
  }
}

extern "C" void kernel_launch(void* const* d_in, const int* in_sizes, int n_in,
                              void* d_out, int out_size, void* d_ws, size_t ws_size,
                              hipStream_t stream) {
  (void)in_sizes; (void)n_in; (void)out_size; (void)ws_size;
  const float* values = (const float*)d_in[0];
  const float* keys   = (const float*)d_in[1];
  const float* query  = (const float*)d_in[2];
  const int*   mask   = (const int*)d_in[3];
  const float* Wv = (const float*)d_in[4];
  const float* Wk = (const float*)d_in[5];
  const float* Wq = (const float*)d_in[6];
  const float* Wo = (const float*)d_in[7];
  const float* bo = (const float*)d_in[8];
  float* out = (float*)d_out;

  constexpr int N = 4, S = 2048, E = 1024;
  constexpr int M = N * S;  // 8192

  // ws layout (bf16): Qb, Kb, Vt, weights, maskbits.  ~58.6 MB.
  short* Qb  = (short*)d_ws;
  short* Kb  = Qb  + (size_t)M * E;
  short* Vtb = Kb  + (size_t)M * E;
  short* Wqb = Vtb + (size_t)M * E;
  short* Wkb = Wqb + (size_t)E * E;
  short* Wvb = Wkb + (size_t)E * E;
  short* Wob = Wvb + (size_t)E * E;
  unsigned* mbits = (unsigned*)(Wob + (size_t)E * E);

  const int n4 = E * E / 4;
  cvt_w<<<n4 / 256, 256, 0, stream>>>(Wq, Wqb, n4);
  cvt_w<<<n4 / 256, 256, 0, stream>>>(Wk, Wkb, n4);
  cvt_w<<<n4 / 256, 256, 0, stream>>>(Wv, Wvb, n4);
  cvt_w<<<n4 / 256, 256, 0, stream>>>(Wo, Wob, n4);
  mask_bits<<<4, 64, 0, stream>>>(mask, mbits);

  const float qsc = 0.125f * 1.4426950408889634f;  // 1/sqrt(D) * log2(e)
  dim3 gg((M / 128) * (E / 128));  // 512 blocks
  gemm_bt<true, 0><<<gg, 256, 0, stream>>>(query,  Wqb, Qb, nullptr, M, E, E, qsc);
  gemm_bt<true, 0><<<gg, 256, 0, stream>>>(keys,   Wkb, Kb, nullptr, M, E, E, 1.0f);
  // V projection lands in d_out (scratch until the final GEMM), then per-head transpose
  gemm_bt<true, 0><<<gg, 256, 0, stream>>>(values, Wvb, (short*)d_out, nullptr, M, E, E, 1.0f);
  vtrans<<<N * 16 * 32, 256, 0, stream>>>((const short*)d_out, Vtb);

  // attention output aliases Qb (each wave consumes its Q rows into registers first)
  attn32<<<64 * (S / 32), 64, 0, stream>>>(Qb, Kb, Vtb, mbits, Qb);

  gemm_bt<false, 1><<<gg, 256, 0, stream>>>(Qb, Wob, out, bo, M, E, E, 1.0f);
}